// Round 5
// baseline (184.858 us; speedup 1.0000x reference)
//
#include <hip/hip_runtime.h>
#include <hip/hip_bf16.h>
#include <math.h>

#define EMBED 384
#define HD 64

typedef unsigned short u16;
typedef unsigned int u32;
using bf16x8 = __attribute__((ext_vector_type(8))) __bf16;
using f32x16 = __attribute__((ext_vector_type(16))) float;

__device__ inline u16 f2bf(float f) {
    union { float f; unsigned u; } v; v.f = f;
    unsigned r = v.u + 0x7fffu + ((v.u >> 16) & 1u);
    return (u16)(r >> 16);
}
__device__ inline bf16x8 ld16(const u16* p) { return *(const bf16x8*)p; }
__device__ inline u32 cvtpk(float lo, float hi) {
    u32 r;
    asm("v_cvt_pk_bf16_f32 %0, %1, %2" : "=v"(r) : "v"(lo), "v"(hi));
    return r;
}
// swap: a.hi-lanes <-> b.lo-lanes  (gfx950 v_permlane32_swap_b32)
__device__ inline void plswap(u32& a, u32& b) {
    asm volatile("v_permlane32_swap_b32 %0, %1" : "+v"(a), "+v"(b));
}

// ---------------- Wt convert: [192 outcols][384 k] bf16; Wq gets qscale*log2e ----------------
__global__ __launch_bounds__(256) void wconv(
    const float* __restrict__ Wk, const float* __restrict__ Wq,
    const float* __restrict__ Wv, u16* __restrict__ Wt)
{
    const int idx = blockIdx.x * 256 + threadIdx.x;
    if (idx >= 192 * EMBED) return;
    const int col = idx / EMBED, k = idx - col * EMBED;
    const int mat = col >> 6, c2 = col & 63;
    const float* W = (mat == 0) ? Wk : (mat == 1) ? Wq : Wv;
    float v = W[k * HD + c2];
    if (mat == 1) v *= 0.051031036307982884f * 1.4426950408889634f;  // 1/sqrt(384)*log2e
    Wt[idx] = f2bf(v);
}

// ---------------- Projection GEMM (swapped): D[outcol][token], col=token ----------------
#define PSTEP(kk, XA, XB, WCUR, WNXT)                                          \
  {                                                                            \
    union { u32 u[4]; bf16x8 v; } bf;                                          \
    bf.u[0] = cvtpk(XA.x, XA.y); bf.u[1] = cvtpk(XA.z, XA.w);                  \
    bf.u[2] = cvtpk(XB.x, XB.y); bf.u[3] = cvtpk(XB.z, XB.w);                  \
    if ((kk) + 1 < 24) {                                                       \
      _Pragma("unroll")                                                        \
      for (int g = 0; g < 6; ++g)                                              \
        WNXT[g] = ld16(wb + (size_t)g * 32 * EMBED + ((kk) + 1) * 16);         \
    }                                                                          \
    _Pragma("unroll")                                                          \
    for (int g = 0; g < 6; ++g)                                                \
      acc[g] = __builtin_amdgcn_mfma_f32_32x32x16_bf16(WCUR[g], bf.v, acc[g], 0, 0, 0); \
    if ((kk) + 4 < 24) {                                                       \
      XA = *(const float4*)(xr + ((kk) + 4) * 16);                             \
      XB = *(const float4*)(xr + ((kk) + 4) * 16 + 4);                         \
    }                                                                          \
  }

__global__ __launch_bounds__(64) void proj_mfma(
    const float* __restrict__ x, const u16* __restrict__ Wt,
    u16* __restrict__ kb, u16* __restrict__ qb, u16* __restrict__ vtb, int T)
{
    const int lane = threadIdx.x;
    const int c = lane & 31, h = lane >> 5;
    const int tok = blockIdx.x * 32 + c;
    const float* xr = x + (size_t)tok * EMBED + 8 * h;
    const u16* wb = Wt + (size_t)c * EMBED + 8 * h;

    f32x16 acc[6];
    #pragma unroll
    for (int g = 0; g < 6; ++g)
        #pragma unroll
        for (int r = 0; r < 16; ++r) acc[g][r] = 0.f;

    float4 x0a = *(const float4*)(xr);
    float4 x0b = *(const float4*)(xr + 4);
    float4 x1a = *(const float4*)(xr + 16);
    float4 x1b = *(const float4*)(xr + 20);
    float4 x2a = *(const float4*)(xr + 32);
    float4 x2b = *(const float4*)(xr + 36);
    float4 x3a = *(const float4*)(xr + 48);
    float4 x3b = *(const float4*)(xr + 52);

    bf16x8 wfA[6], wfB[6];
    #pragma unroll
    for (int g = 0; g < 6; ++g) wfA[g] = ld16(wb + (size_t)g * 32 * EMBED);

    for (int k4 = 0; k4 < 24; k4 += 4) {
        PSTEP(k4 + 0, x0a, x0b, wfA, wfB)
        PSTEP(k4 + 1, x1a, x1b, wfB, wfA)
        PSTEP(k4 + 2, x2a, x2b, wfA, wfB)
        PSTEP(k4 + 3, x3a, x3b, wfB, wfA)
    }

    #pragma unroll
    for (int mat = 0; mat < 2; ++mat) {
        u16* dst = (mat == 0) ? kb : qb;
        #pragma unroll
        for (int dg = 0; dg < 2; ++dg) {
            const f32x16 a = acc[mat * 2 + dg];
            #pragma unroll
            for (int k2 = 0; k2 < 4; ++k2) {
                u32 pair[2];
                pair[0] = cvtpk(a[4 * k2], a[4 * k2 + 1]);
                pair[1] = cvtpk(a[4 * k2 + 2], a[4 * k2 + 3]);
                *(uint2*)(dst + (size_t)tok * HD + dg * 32 + 8 * k2 + 4 * h) = *(uint2*)pair;
            }
        }
    }
    const int bb = tok / T, trow = tok - bb * T;
    u16* vb = vtb + (size_t)bb * HD * T + trow;
    #pragma unroll
    for (int dg = 0; dg < 2; ++dg) {
        const f32x16 a = acc[4 + dg];
        #pragma unroll
        for (int r = 0; r < 16; ++r) {
            const int dim = (r & 3) + 8 * (r >> 2) + 4 * h + 32 * dg;
            vb[(size_t)dim * T] = f2bf(a[r]);
        }
    }
}

// ---------------- Flash attention: 32-row qtiles, 4-way key-split, K-prefetch pipeline ----------------
#define LOADK(KF0, KF1, KF2, KF3, S)                                            \
  { const u16* kp_ = kbase + (size_t)(32 * (S) + c) * HD + 8 * h;               \
    KF0 = ld16(kp_); KF1 = ld16(kp_ + 16); KF2 = ld16(kp_ + 32); KF3 = ld16(kp_ + 48); }

#define COMPUTE(KF0, KF1, KF2, KF3, S)                                          \
  { const u16* vp_ = vtbase + (size_t)c * T + 32 * (S) + 8 * h;                 \
    const bf16x8 vf00 = ld16(vp_), vf01 = ld16(vp_ + 16);                       \
    const u16* vp2_ = vp_ + (size_t)32 * T;                                     \
    const bf16x8 vf10 = ld16(vp2_), vf11 = ld16(vp2_ + 16);                     \
    f32x16 st;                                                                  \
    _Pragma("unroll")                                                           \
    for (int r = 0; r < 16; ++r) st[r] = 0.f;                                   \
    __builtin_amdgcn_s_setprio(1);                                              \
    st = __builtin_amdgcn_mfma_f32_32x32x16_bf16(KF0, qf0, st, 0, 0, 0);        \
    st = __builtin_amdgcn_mfma_f32_32x32x16_bf16(KF1, qf1, st, 0, 0, 0);        \
    st = __builtin_amdgcn_mfma_f32_32x32x16_bf16(KF2, qf2, st, 0, 0, 0);        \
    st = __builtin_amdgcn_mfma_f32_32x32x16_bf16(KF3, qf3, st, 0, 0, 0);        \
    __builtin_amdgcn_s_setprio(0);                                              \
    if ((S) == q32) {                                                           \
      _Pragma("unroll")                                                         \
      for (int r = 0; r < 16; ++r) {                                            \
        const int key = (r & 3) + 8 * (r >> 2) + 4 * h;                         \
        if (key > c) st[r] = -INFINITY;                                         \
      }                                                                         \
    }                                                                           \
    float tm = fmaxf(st[0], st[1]);                                             \
    _Pragma("unroll")                                                           \
    for (int r = 2; r < 16; ++r) tm = fmaxf(tm, st[r]);                         \
    tm = fmaxf(tm, __shfl_xor(tm, 32));                                         \
    if (__any(tm > m + 11.5f)) {                                                \
      const float mn = fmaxf(m, tm);                                            \
      const float corr = exp2f(m - mn);                                         \
      m = mn;                                                                   \
      lsum *= corr;                                                             \
      _Pragma("unroll")                                                         \
      for (int r = 0; r < 16; ++r) { o0[r] *= corr; o1[r] *= corr; }            \
    }                                                                           \
    float ps = 0.f;                                                             \
    _Pragma("unroll")                                                           \
    for (int r = 0; r < 16; ++r) { st[r] = exp2f(st[r] - m); ps += st[r]; }     \
    lsum += ps + __shfl_xor(ps, 32);                                            \
    u32 w[8];                                                                   \
    _Pragma("unroll")                                                           \
    for (int q = 0; q < 8; ++q) w[q] = cvtpk(st[2 * q], st[2 * q + 1]);         \
    {                                                                           \
      u32 a0 = w[0], b0 = w[2], a1 = w[1], b1 = w[3];                           \
      plswap(a0, b0); plswap(a1, b1);                                           \
      union { u32 u[4]; bf16x8 v; } pf;                                         \
      pf.u[0] = a0; pf.u[1] = a1; pf.u[2] = b0; pf.u[3] = b1;                   \
      __builtin_amdgcn_s_setprio(1);                                            \
      o0 = __builtin_amdgcn_mfma_f32_32x32x16_bf16(vf00, pf.v, o0, 0, 0, 0);    \
      o1 = __builtin_amdgcn_mfma_f32_32x32x16_bf16(vf10, pf.v, o1, 0, 0, 0);    \
      __builtin_amdgcn_s_setprio(0);                                            \
    }                                                                           \
    {                                                                           \
      u32 a0 = w[4], b0 = w[6], a1 = w[5], b1 = w[7];                           \
      plswap(a0, b0); plswap(a1, b1);                                           \
      union { u32 u[4]; bf16x8 v; } pf;                                         \
      pf.u[0] = a0; pf.u[1] = a1; pf.u[2] = b0; pf.u[3] = b1;                   \
      __builtin_amdgcn_s_setprio(1);                                            \
      o0 = __builtin_amdgcn_mfma_f32_32x32x16_bf16(vf01, pf.v, o0, 0, 0, 0);    \
      o1 = __builtin_amdgcn_mfma_f32_32x32x16_bf16(vf11, pf.v, o1, 0, 0, 0);    \
      __builtin_amdgcn_s_setprio(0);                                            \
    }                                                                           \
  }

__global__ __launch_bounds__(256) void attn_mfma(
    const u16* __restrict__ qb, const u16* __restrict__ kb,
    const u16* __restrict__ vtb, float* __restrict__ out, int T)
{
    __shared__ float slab[4][HD][32];   // 32 KB, [wave][dim][row]
    __shared__ float ml2[2][4][32];
    __shared__ float linv_s[32];

    const int b    = blockIdx.x;
    const int q32  = gridDim.y - 1 - blockIdx.y;     // heavy first
    const int qs   = q32 * 32;
    const int wv   = threadIdx.x >> 6;
    const int lane = threadIdx.x & 63;
    const int c = lane & 31, h = lane >> 5;

    // Q B-frags (log2-units: scale folded into Wq)
    const u16* qp = qb + ((size_t)b * T + qs + c) * HD + 8 * h;
    const bf16x8 qf0 = ld16(qp), qf1 = ld16(qp + 16);
    const bf16x8 qf2 = ld16(qp + 32), qf3 = ld16(qp + 48);

    f32x16 o0, o1;
    #pragma unroll
    for (int r = 0; r < 16; ++r) { o0[r] = 0.f; o1[r] = 0.f; }
    float m = -INFINITY, lsum = 0.f;

    const u16* kbase  = kb  + (size_t)b * T * HD;
    const u16* vtbase = vtb + (size_t)b * HD * T;

    bf16x8 kA0, kA1, kA2, kA3, kB0, kB1, kB2, kB3;
    int s = wv;
    if (s <= q32) {
        LOADK(kA0, kA1, kA2, kA3, s)
        for (;;) {
            const int sn = s + 4;
            const bool hn = sn <= q32;
            if (hn) { LOADK(kB0, kB1, kB2, kB3, sn) }
            COMPUTE(kA0, kA1, kA2, kA3, s)
            if (!hn) break;
            const int sn2 = sn + 4;
            const bool hn2 = sn2 <= q32;
            if (hn2) { LOADK(kA0, kA1, kA2, kA3, sn2) }
            COMPUTE(kB0, kB1, kB2, kB3, sn)
            if (!hn2) break;
            s = sn2;
        }
    }

    // ---- cross-wave merge ----
    if (h == 0) { ml2[0][wv][c] = m; ml2[1][wv][c] = lsum; }
    __syncthreads();
    float M = -INFINITY;
    #pragma unroll
    for (int i = 0; i < 4; ++i) M = fmaxf(M, ml2[0][i][c]);
    float L = 0.f;
    #pragma unroll
    for (int i = 0; i < 4; ++i) L += ml2[1][i][c] * exp2f(ml2[0][i][c] - M);
    const float coef = exp2f(m - M);
    if (wv == 0 && h == 0) linv_s[c] = 1.f / L;
    #pragma unroll
    for (int r = 0; r < 16; ++r) {
        const int d0 = (r & 3) + 8 * (r >> 2) + 4 * h;
        slab[wv][d0][c]      = o0[r] * coef;
        slab[wv][d0 + 32][c] = o1[r] * coef;
    }
    __syncthreads();

    float res[8];
    #pragma unroll
    for (int j = 0; j < 8; ++j) {
        const int d = 16 * wv + 8 * h + j;
        res[j] = slab[0][d][c] + slab[1][d][c] + slab[2][d][c] + slab[3][d][c];
    }
    const float li = linv_s[c];
    float4 s0 = {res[0] * li, res[1] * li, res[2] * li, res[3] * li};
    float4 s1 = {res[4] * li, res[5] * li, res[6] * li, res[7] * li};
    float* op = out + ((size_t)b * T + qs + c) * HD + 16 * wv + 8 * h;
    *(float4*)op = s0;
    *(float4*)(op + 4) = s1;
}

extern "C" void kernel_launch(void* const* d_in, const int* in_sizes, int n_in,
                              void* d_out, int out_size, void* d_ws, size_t ws_size,
                              hipStream_t stream) {
    const float* x  = (const float*)d_in[0];
    const float* Wk = (const float*)d_in[1];
    const float* Wq = (const float*)d_in[2];
    const float* Wv = (const float*)d_in[3];
    float* out = (float*)d_out;

    const int M = in_sizes[0] / EMBED;   // B*T = 32768
    const int B = 8;
    const int T = M / B;                 // 4096

    u16* kb  = (u16*)d_ws;
    u16* qb  = kb + (size_t)M * HD;
    u16* vtb = qb + (size_t)M * HD;              // [B][HD][T]
    u16* Wt  = vtb + (size_t)M * HD;             // [192][384]

    wconv<<<(192 * EMBED + 255) / 256, 256, 0, stream>>>(Wk, Wq, Wv, Wt);
    proj_mfma<<<M / 32, 64, 0, stream>>>(x, Wt, kb, qb, vtb, T);
    dim3 g(B, T / 32);
    attn_mfma<<<g, 256, 0, stream>>>(qb, kb, vtb, out, T);
}

// Round 10
// 167.524 us; speedup vs baseline: 1.1035x; 1.1035x over previous
//
#include <hip/hip_runtime.h>
#include <hip/hip_bf16.h>
#include <math.h>

#define EMBED 384
#define HD 64

typedef unsigned short u16;
typedef unsigned int u32;
using bf16x8 = __attribute__((ext_vector_type(8))) __bf16;
using f32x16 = __attribute__((ext_vector_type(16))) float;

__device__ inline u16 f2bf(float f) {
    union { float f; unsigned u; } v; v.f = f;
    unsigned r = v.u + 0x7fffu + ((v.u >> 16) & 1u);
    return (u16)(r >> 16);
}
__device__ inline bf16x8 ld16(const u16* p) { return *(const bf16x8*)p; }
__device__ inline u32 cvtpk(float lo, float hi) {
    u32 r;
    asm("v_cvt_pk_bf16_f32 %0, %1, %2" : "=v"(r) : "v"(lo), "v"(hi));
    return r;
}
// R4-proven exact pattern
__device__ inline void plswap(u32& a, u32& b) {
    asm volatile("v_permlane32_swap_b32 %0, %1" : "+v"(a), "+v"(b));
}

// ---------------- R4-verbatim wconv: Wt row-major [192 outcols][384 k]; Wq scaled ----------------
__global__ __launch_bounds__(256) void wconv(
    const float* __restrict__ Wk, const float* __restrict__ Wq,
    const float* __restrict__ Wv, u16* __restrict__ Wt)
{
    const int idx = blockIdx.x * 256 + threadIdx.x;
    if (idx >= 192 * EMBED) return;
    const int col = idx / EMBED, k = idx - col * EMBED;
    const int mat = col >> 6, c2 = col & 63;
    const float* W = (mat == 0) ? Wk : (mat == 1) ? Wq : Wv;
    float v = W[k * HD + c2];
    if (mat == 1) v *= 0.051031036307982884f * 1.4426950408889634f;  // 1/sqrt(384)*log2e
    Wt[idx] = f2bf(v);
}

// ---------------- R4-verbatim projection GEMM (1-wave blocks, 32 tokens, acc[6]) ----------------
#define PSTEP(kk, XA, XB, WCUR, WNXT)                                          \
  {                                                                            \
    union { u32 u[4]; bf16x8 v; } bf;                                          \
    bf.u[0] = cvtpk(XA.x, XA.y); bf.u[1] = cvtpk(XA.z, XA.w);                  \
    bf.u[2] = cvtpk(XB.x, XB.y); bf.u[3] = cvtpk(XB.z, XB.w);                  \
    if ((kk) + 1 < 24) {                                                       \
      _Pragma("unroll")                                                        \
      for (int g = 0; g < 6; ++g)                                              \
        WNXT[g] = ld16(wb + (size_t)g * 32 * EMBED + ((kk) + 1) * 16);         \
    }                                                                          \
    _Pragma("unroll")                                                          \
    for (int g = 0; g < 6; ++g)                                                \
      acc[g] = __builtin_amdgcn_mfma_f32_32x32x16_bf16(WCUR[g], bf.v, acc[g], 0, 0, 0); \
    if ((kk) + 4 < 24) {                                                       \
      XA = *(const float4*)(xr + ((kk) + 4) * 16);                             \
      XB = *(const float4*)(xr + ((kk) + 4) * 16 + 4);                         \
    }                                                                          \
  }

__global__ __launch_bounds__(64) void proj_mfma(
    const float* __restrict__ x, const u16* __restrict__ Wt,
    u16* __restrict__ kb, u16* __restrict__ qb, u16* __restrict__ vtb, int T)
{
    const int lane = threadIdx.x;
    const int c = lane & 31, h = lane >> 5;
    const int tok = blockIdx.x * 32 + c;
    const float* xr = x + (size_t)tok * EMBED + 8 * h;
    const u16* wb = Wt + (size_t)c * EMBED + 8 * h;

    f32x16 acc[6];
    #pragma unroll
    for (int g = 0; g < 6; ++g)
        #pragma unroll
        for (int r = 0; r < 16; ++r) acc[g][r] = 0.f;

    float4 x0a = *(const float4*)(xr);
    float4 x0b = *(const float4*)(xr + 4);
    float4 x1a = *(const float4*)(xr + 16);
    float4 x1b = *(const float4*)(xr + 20);
    float4 x2a = *(const float4*)(xr + 32);
    float4 x2b = *(const float4*)(xr + 36);
    float4 x3a = *(const float4*)(xr + 48);
    float4 x3b = *(const float4*)(xr + 52);

    bf16x8 wfA[6], wfB[6];
    #pragma unroll
    for (int g = 0; g < 6; ++g) wfA[g] = ld16(wb + (size_t)g * 32 * EMBED);

    for (int k4 = 0; k4 < 24; k4 += 4) {
        PSTEP(k4 + 0, x0a, x0b, wfA, wfB)
        PSTEP(k4 + 1, x1a, x1b, wfB, wfA)
        PSTEP(k4 + 2, x2a, x2b, wfA, wfB)
        PSTEP(k4 + 3, x3a, x3b, wfB, wfA)
    }

    #pragma unroll
    for (int mat = 0; mat < 2; ++mat) {
        u16* dst = (mat == 0) ? kb : qb;
        #pragma unroll
        for (int dg = 0; dg < 2; ++dg) {
            const f32x16 a = acc[mat * 2 + dg];
            #pragma unroll
            for (int k2 = 0; k2 < 4; ++k2) {
                u32 pair[2];
                pair[0] = cvtpk(a[4 * k2], a[4 * k2 + 1]);
                pair[1] = cvtpk(a[4 * k2 + 2], a[4 * k2 + 3]);
                *(uint2*)(dst + (size_t)tok * HD + dg * 32 + 8 * k2 + 4 * h) = *(uint2*)pair;
            }
        }
    }
    const int bb = tok / T, trow = tok - bb * T;
    u16* vb = vtb + (size_t)bb * HD * T + trow;
    #pragma unroll
    for (int dg = 0; dg < 2; ++dg) {
        const f32x16 a = acc[4 + dg];
        #pragma unroll
        for (int r = 0; r < 16; ++r) {
            const int dim = (r & 3) + 8 * (r >> 2) + 4 * h + 32 * dg;
            vb[(size_t)dim * T] = f2bf(a[r]);
        }
    }
}

// ---------------- repack: row-major K / V^T -> frag-major, via the READER's formulas ----------------
// kfb[((bt*4 + j)*64 + lane)*8 + e] = K[b][key=32S+(lane&31)][dim=j*16+8*(lane>>5)+e]
// vfb[((bt*4 + f)*64 + lane)*8 + e] = V[b][key=32S+(f&1)*16+8*(lane>>5)+e][dim=(f>>1)*32+(lane&31)]
__global__ __launch_bounds__(256) void repack(
    const u16* __restrict__ kb, const u16* __restrict__ vtb,
    u16* __restrict__ kfb, u16* __restrict__ vfb, int T)
{
    const int tid = blockIdx.x * 256 + threadIdx.x;    // 0 .. 524287
    const int half = tid >> 18;                        // M*HD/8 = 262144 = 2^18
    const int fl8 = tid & 262143;
    const size_t fl = (size_t)fl8 * 8;
    const int lane = fl8 & 63;
    const int fj   = (fl8 >> 6) & 3;
    const int bt   = fl8 >> 8;                         // global 32-key subtile
    const int b = bt >> 7, S = bt & 127;
    const int c = lane & 31, h = lane >> 5;
    if (half == 0) {
        const u16* src = kb + ((size_t)b * T + 32 * S + c) * 64 + fj * 16 + 8 * h;
        *(uint4*)(kfb + fl) = *(const uint4*)src;
    } else {
        const int dim = (fj >> 1) * 32 + c;
        const int key = 32 * S + (fj & 1) * 16 + 8 * h;
        const u16* src = vtb + (size_t)b * HD * T + (size_t)dim * T + key;
        *(uint4*)(vfb + fl) = *(const uint4*)src;
    }
}

// ---------------- R9-verbatim flash attention: frag-major dense loads ----------------
#define LOADK(KF0, KF1, KF2, KF3, S)                                            \
  { const u16* kp_ = kbase2 + (size_t)(S) * 2048 + lane8;                       \
    KF0 = ld16(kp_); KF1 = ld16(kp_ + 512); KF2 = ld16(kp_ + 1024); KF3 = ld16(kp_ + 1536); }

#define COMPUTE(KF0, KF1, KF2, KF3, S)                                          \
  { const u16* vp_ = vbase2 + (size_t)(S) * 2048 + lane8;                       \
    const bf16x8 vf00 = ld16(vp_),        vf01 = ld16(vp_ + 512);               \
    const bf16x8 vf10 = ld16(vp_ + 1024), vf11 = ld16(vp_ + 1536);              \
    f32x16 st;                                                                  \
    _Pragma("unroll")                                                           \
    for (int r = 0; r < 16; ++r) st[r] = 0.f;                                   \
    __builtin_amdgcn_s_setprio(1);                                              \
    st = __builtin_amdgcn_mfma_f32_32x32x16_bf16(KF0, qf0, st, 0, 0, 0);        \
    st = __builtin_amdgcn_mfma_f32_32x32x16_bf16(KF1, qf1, st, 0, 0, 0);        \
    st = __builtin_amdgcn_mfma_f32_32x32x16_bf16(KF2, qf2, st, 0, 0, 0);        \
    st = __builtin_amdgcn_mfma_f32_32x32x16_bf16(KF3, qf3, st, 0, 0, 0);        \
    __builtin_amdgcn_s_setprio(0);                                              \
    if ((S) == q32) {                                                           \
      _Pragma("unroll")                                                         \
      for (int r = 0; r < 16; ++r) {                                            \
        const int key = (r & 3) + 8 * (r >> 2) + 4 * h;                         \
        if (key > c) st[r] = -INFINITY;                                         \
      }                                                                         \
    }                                                                           \
    float tm;                                                                   \
    { float a0 = fmaxf(st[0], st[1]),  a1 = fmaxf(st[2], st[3]);                \
      float a2 = fmaxf(st[4], st[5]),  a3 = fmaxf(st[6], st[7]);                \
      float a4 = fmaxf(st[8], st[9]),  a5 = fmaxf(st[10], st[11]);              \
      float a6 = fmaxf(st[12], st[13]), a7 = fmaxf(st[14], st[15]);             \
      a0 = fmaxf(a0, a1); a2 = fmaxf(a2, a3); a4 = fmaxf(a4, a5); a6 = fmaxf(a6, a7); \
      tm = fmaxf(fmaxf(a0, a2), fmaxf(a4, a6)); }                               \
    tm = fmaxf(tm, __shfl_xor(tm, 32));                                         \
    if (__any(tm > m + 11.5f)) {                                                \
      const float mn = fmaxf(m, tm);                                            \
      const float corr = exp2f(m - mn);                                         \
      m = mn;                                                                   \
      lsum *= corr;                                                             \
      _Pragma("unroll")                                                         \
      for (int r = 0; r < 16; ++r) { o0[r] *= corr; o1[r] *= corr; }            \
    }                                                                           \
    _Pragma("unroll")                                                           \
    for (int r = 0; r < 16; ++r) st[r] = exp2f(st[r] - m);                      \
    float ps;                                                                   \
    { float a0 = st[0] + st[1],  a1 = st[2] + st[3];                            \
      float a2 = st[4] + st[5],  a3 = st[6] + st[7];                            \
      float a4 = st[8] + st[9],  a5 = st[10] + st[11];                          \
      float a6 = st[12] + st[13], a7 = st[14] + st[15];                         \
      a0 += a1; a2 += a3; a4 += a5; a6 += a7;                                   \
      ps = (a0 + a2) + (a4 + a6); }                                             \
    lsum += ps + __shfl_xor(ps, 32);                                            \
    u32 w[8];                                                                   \
    _Pragma("unroll")                                                           \
    for (int q = 0; q < 8; ++q) w[q] = cvtpk(st[2 * q], st[2 * q + 1]);         \
    {                                                                           \
      u32 a0 = w[0], b0 = w[2], a1 = w[1], b1 = w[3];                           \
      plswap(a0, b0); plswap(a1, b1);                                           \
      union { u32 u[4]; bf16x8 v; } pf;                                         \
      pf.u[0] = a0; pf.u[1] = a1; pf.u[2] = b0; pf.u[3] = b1;                   \
      __builtin_amdgcn_s_setprio(1);                                            \
      o0 = __builtin_amdgcn_mfma_f32_32x32x16_bf16(vf00, pf.v, o0, 0, 0, 0);    \
      o1 = __builtin_amdgcn_mfma_f32_32x32x16_bf16(vf10, pf.v, o1, 0, 0, 0);    \
      __builtin_amdgcn_s_setprio(0);                                            \
    }                                                                           \
    {                                                                           \
      u32 a0 = w[4], b0 = w[6], a1 = w[5], b1 = w[7];                           \
      plswap(a0, b0); plswap(a1, b1);                                           \
      union { u32 u[4]; bf16x8 v; } pf;                                         \
      pf.u[0] = a0; pf.u[1] = a1; pf.u[2] = b0; pf.u[3] = b1;                   \
      __builtin_amdgcn_s_setprio(1);                                            \
      o0 = __builtin_amdgcn_mfma_f32_32x32x16_bf16(vf01, pf.v, o0, 0, 0, 0);    \
      o1 = __builtin_amdgcn_mfma_f32_32x32x16_bf16(vf11, pf.v, o1, 0, 0, 0);    \
      __builtin_amdgcn_s_setprio(0);                                            \
    }                                                                           \
  }

__global__ __launch_bounds__(256) void attn_mfma(
    const u16* __restrict__ qb, const u16* __restrict__ kfb,
    const u16* __restrict__ vfb, float* __restrict__ out, int T)
{
    __shared__ float slab[4][HD][32];   // 32 KB, [wave][dim][row]
    __shared__ float ml2[2][4][32];
    __shared__ float linv_s[32];

    const int b    = blockIdx.x;
    const int q32  = gridDim.y - 1 - blockIdx.y;     // heavy first
    const int qs   = q32 * 32;
    const int wv   = threadIdx.x >> 6;
    const int lane = threadIdx.x & 63;
    const int c = lane & 31, h = lane >> 5;
    const int lane8 = lane * 8;

    // Q B-frags (log2-units: scale folded into Wq)
    const u16* qp = qb + ((size_t)b * T + qs + c) * HD + 8 * h;
    const bf16x8 qf0 = ld16(qp), qf1 = ld16(qp + 16);
    const bf16x8 qf2 = ld16(qp + 32), qf3 = ld16(qp + 48);

    f32x16 o0, o1;
    #pragma unroll
    for (int r = 0; r < 16; ++r) { o0[r] = 0.f; o1[r] = 0.f; }
    float m = -INFINITY, lsum = 0.f;

    const u16* kbase2 = kfb + (size_t)b * T * HD;
    const u16* vbase2 = vfb + (size_t)b * T * HD;

    bf16x8 kA0, kA1, kA2, kA3, kB0, kB1, kB2, kB3;
    int s = wv;
    if (s <= q32) {
        LOADK(kA0, kA1, kA2, kA3, s)
        for (;;) {
            const int sn = s + 4;
            const bool hn = sn <= q32;
            if (hn) { LOADK(kB0, kB1, kB2, kB3, sn) }
            COMPUTE(kA0, kA1, kA2, kA3, s)
            if (!hn) break;
            const int sn2 = sn + 4;
            const bool hn2 = sn2 <= q32;
            if (hn2) { LOADK(kA0, kA1, kA2, kA3, sn2) }
            COMPUTE(kB0, kB1, kB2, kB3, sn)
            if (!hn2) break;
            s = sn2;
        }
    }

    // ---- cross-wave merge ----
    if (h == 0) { ml2[0][wv][c] = m; ml2[1][wv][c] = lsum; }
    __syncthreads();
    float M = -INFINITY;
    #pragma unroll
    for (int i = 0; i < 4; ++i) M = fmaxf(M, ml2[0][i][c]);
    float L = 0.f;
    #pragma unroll
    for (int i = 0; i < 4; ++i) L += ml2[1][i][c] * exp2f(ml2[0][i][c] - M);
    const float coef = exp2f(m - M);
    if (wv == 0 && h == 0) linv_s[c] = 1.f / L;
    #pragma unroll
    for (int r = 0; r < 16; ++r) {
        const int d0 = (r & 3) + 8 * (r >> 2) + 4 * h;
        slab[wv][d0][c]      = o0[r] * coef;
        slab[wv][d0 + 32][c] = o1[r] * coef;
    }
    __syncthreads();

    float res[8];
    #pragma unroll
    for (int j = 0; j < 8; ++j) {
        const int d = 16 * wv + 8 * h + j;
        res[j] = slab[0][d][c] + slab[1][d][c] + slab[2][d][c] + slab[3][d][c];
    }
    const float li = linv_s[c];
    float4 s0 = {res[0] * li, res[1] * li, res[2] * li, res[3] * li};
    float4 s1 = {res[4] * li, res[5] * li, res[6] * li, res[7] * li};
    float* op = out + ((size_t)b * T + qs + c) * HD + 16 * wv + 8 * h;
    *(float4*)op = s0;
    *(float4*)(op + 4) = s1;
}

extern "C" void kernel_launch(void* const* d_in, const int* in_sizes, int n_in,
                              void* d_out, int out_size, void* d_ws, size_t ws_size,
                              hipStream_t stream) {
    const float* x  = (const float*)d_in[0];
    const float* Wk = (const float*)d_in[1];
    const float* Wq = (const float*)d_in[2];
    const float* Wv = (const float*)d_in[3];
    float* out = (float*)d_out;

    const int M = in_sizes[0] / EMBED;   // B*T = 32768
    const int B = 8;
    const int T = M / B;                 // 4096

    // ws: frag-major buffers + Q + Wt (12.3 MB, proven size)
    u16* kfb = (u16*)d_ws;                       // frag-major K  [B][T/32][4][64][8]
    u16* qb  = kfb + (size_t)M * HD;             // row-major Q   [M][64]
    u16* vfb = qb + (size_t)M * HD;              // frag-major V
    u16* Wt  = vfb + (size_t)M * HD;             // row-major W^T [192][384]
    // d_out as scratch for R4-layout staging (fully overwritten by attn epilogue)
    u16* kb  = (u16*)d_out;                      // row-major K   [M][64]  (4 MB)
    u16* vtb = kb + (size_t)M * HD;              // V^T           [B][HD][T] (4 MB)

    wconv<<<(192 * EMBED + 255) / 256, 256, 0, stream>>>(Wk, Wq, Wv, Wt);
    proj_mfma<<<M / 32, 64, 0, stream>>>(x, Wt, kb, qb, vtb, T);
    repack<<<2048, 256, 0, stream>>>(kb, vtb, kfb, vfb, T);
    dim3 g(B, T / 32);
    attn_mfma<<<g, 256, 0, stream>>>(qb, kfb, vfb, out, T);
}